// Round 11
// baseline (2055.956 us; speedup 1.0000x reference)
//
#include <hip/hip_runtime.h>
#include <hip/hip_bf16.h>
#include <hip/hip_fp16.h>

#define DIM 768
#define SLEN 4096
#define BATCH 4
#define NTILES 528   // 128-granular causal tiles per batch (S layout)
#define NT256 136    // 256-granular causal tiles per batch (qk grid)
#define SPB ((size_t)NTILES * 16384)

typedef __attribute__((ext_vector_type(8))) short short8;
typedef __attribute__((ext_vector_type(4))) short short4v;
typedef __attribute__((ext_vector_type(4))) float f32x4;
typedef __attribute__((ext_vector_type(8))) _Float16 f16x8;

typedef __attribute__((address_space(1))) void gvoid;
typedef __attribute__((address_space(3))) void lvoid;

__device__ __forceinline__ void gl_lds16(const void* g, void* l) {
  __builtin_amdgcn_global_load_lds((gvoid*)g, (lvoid*)l, 16, 0, 0);
}

__device__ __forceinline__ unsigned short f2h(float x) {
  union { _Float16 h; unsigned short u; } c; c.h = (_Float16)x; return c.u;
}
__device__ __forceinline__ float h2f(unsigned short u) {
  union { _Float16 h; unsigned short u; } c; c.u = u; return (float)c.h;
}

union V8 { short8 v; unsigned short u[8]; };

// ---------------- kernel 1: x fp32 -> fp16 ----------------
__global__ __launch_bounds__(256) void convert_x_kernel(
    const float* __restrict__ x, unsigned short* __restrict__ xb) {
  size_t i = ((size_t)blockIdx.x * 256 + threadIdx.x) * 8;
  f32x4 a = *(const f32x4*)(x + i);
  f32x4 b = *(const f32x4*)(x + i + 4);
  V8 o;
#pragma unroll
  for (int j = 0; j < 4; ++j) { o.u[j] = f2h(a[j]); o.u[4 + j] = f2h(b[j]); }
  *(short8*)(xb + i) = o.v;
}

// ---------------- kernel 2: W [k][n] fp32 -> Wt [n][k] fp16 ----------------
__global__ __launch_bounds__(256) void transpose_w_kernel(
    const float* __restrict__ Wq, const float* __restrict__ Wk,
    const float* __restrict__ Wv, unsigned short* __restrict__ Wt) {
  __shared__ float Tl[32][33];
  const float* Wi = blockIdx.z == 0 ? Wq : (blockIdx.z == 1 ? Wk : Wv);
  unsigned short* Wo = Wt + (size_t)blockIdx.z * DIM * DIM;
  int k0 = blockIdx.x * 32, n0 = blockIdx.y * 32;
  int t = threadIdx.x;
  int r = t >> 3, c4 = (t & 7) * 4;
  f32x4 v = *(const f32x4*)(Wi + (size_t)(k0 + r) * DIM + n0 + c4);
#pragma unroll
  for (int j = 0; j < 4; ++j) Tl[r][c4 + j] = v[j];
  __syncthreads();
  short4v ov;
#pragma unroll
  for (int j = 0; j < 4; ++j) ov[j] = (short)f2h(Tl[c4 + j][r]);
  *(short4v*)(Wo + (size_t)(n0 + r) * DIM + k0 + c4) = ov;
}

// ====== 256x256 GEMM core, BK=32, double-buffer 64 KiB -> 2 blocks/CU ======
// Round-10 post-mortem: ring-3 counted vmcnt at 1 block/CU regressed — the wall
// is per-barrier fixed cost with only 2 waves/SIMD. This round buys occupancy:
// 64 KiB LDS (2 bufs x 32 KiB) -> 2 blocks/CU (4 waves/SIMD); cross-block
// overlap absorbs barrier/drain stalls (m97/m114 mechanism). Drain-0 per tile.
// LDS buf p @ p*32768: A [256][32] (two 8KB halves) + B [256][32] @ +16384.
// Swizzle: 16B chunk c of row r at slot c ^ ((r>>1)&3); staged via
// inverse-swizzled global source. Fragment-read key (l15>>1)&3 (lane-only);
// 2-way banks = free. Per tile t: {4 B + 4 A-low reads ∥ stage(t+1)->other buf
// -> lgkm(4) -> 16 MFMA -> (4 A-high reads) lgkm(0) -> 16 MFMA -> vmcnt(0) ->
// barrier}. Round-4 sync rule: own-drain precedes barrier precedes cross-wave
// ds_read of the staged buffer.

#define STAGEH(srcp, stride, ldsoff)                                              \
  gl_lds16((srcp) + (size_t)(t >> 2) * (stride) + cH, ldsb + (ldsoff) + t * 16);

#define STG_AB(Aptr, Bptr, stride, OFF)                                           \
  STAGEH((Aptr), (stride), (OFF));                                                \
  STAGEH((Aptr) + 128 * (stride), (stride), (OFF) + 8192);                        \
  STAGEH((Bptr), (stride), (OFF) + 16384);                                        \
  STAGEH((Bptr) + 128 * (stride), (stride), (OFF) + 24576);

#define STG_PV(pa0, pa1, Bptr, OFF)                                               \
  STAGEH((pa0), 128, (OFF));                                                      \
  STAGEH((pa1), 128, (OFF) + 8192);                                               \
  STAGEH((Bptr), SLEN, (OFF) + 16384);                                            \
  STAGEH((Bptr) + 128 * SLEN, SLEN, (OFF) + 24576);

#define RD_A(dst, aoff)                                                           \
  _Pragma("unroll") for (int j = 0; j < 4; ++j)                                   \
      dst[j] = __builtin_bit_cast(f16x8,                                          \
               *(const short8*)(ldsb + arb + (aoff) + j * 1024));

#define RD_B(dst, boff)                                                           \
  _Pragma("unroll") for (int n = 0; n < 4; ++n)                                   \
      dst[n] = __builtin_bit_cast(f16x8,                                          \
               *(const short8*)(ldsb + brb + (boff) + n * 1024));

#define LGKM(N)                                                                   \
  asm volatile("s_waitcnt lgkmcnt(" #N ")" ::: "memory");                         \
  __builtin_amdgcn_sched_barrier(0);

#define TILE32(AOFF, STG, VMW, BAR)                                               \
  {                                                                               \
    f16x8 fb_[4], fl_[4], fh_[4];                                                 \
    RD_B(fb_, (AOFF) + 16384);                                                    \
    RD_A(fl_, (AOFF));                                                            \
    STG;                                                                          \
    RD_A(fh_, (AOFF) + 4096);                                                     \
    LGKM(4);                                                                      \
    __builtin_amdgcn_s_setprio(1);                                                \
    _Pragma("unroll") for (int j = 0; j < 4; ++j)                                 \
      _Pragma("unroll") for (int n = 0; n < 4; ++n)                               \
        acc[j][n] = __builtin_amdgcn_mfma_f32_16x16x32_f16(                       \
            fl_[j], fb_[n], acc[j][n], 0, 0, 0);                                  \
    __builtin_amdgcn_s_setprio(0);                                                \
    LGKM(0);                                                                      \
    __builtin_amdgcn_s_setprio(1);                                                \
    _Pragma("unroll") for (int j = 0; j < 4; ++j)                                 \
      _Pragma("unroll") for (int n = 0; n < 4; ++n)                               \
        acc[4 + j][n] = __builtin_amdgcn_mfma_f32_16x16x32_f16(                   \
            fh_[j], fb_[n], acc[4 + j][n], 0, 0, 0);                              \
    __builtin_amdgcn_s_setprio(0);                                                \
    VMW;                                                                          \
    BAR;                                                                          \
  }

#define VMC0 asm volatile("s_waitcnt vmcnt(0)" ::: "memory")
#define SBAR asm volatile("s_barrier" ::: "memory")

// MODE 0: merged qkv. grid 576 XCD-swizzled. z<2: C=A(xb)xB(wt_z)^T -> Q/K.
//         z==2: Vt[e][s] = A(wt_v) x B(xb)^T (swapped roles, out ld=SLEN).
// MODE 1: causal qk 256-tiles (XCD-swizzled per batch) -> packed-128 S scatter.
template <int MODE>
__global__ __launch_bounds__(512, 4) void gemm8_kernel(
    const unsigned short* __restrict__ Ag, const unsigned short* __restrict__ Bg,
    unsigned short* __restrict__ o0, unsigned short* __restrict__ o1,
    unsigned short* __restrict__ o2, size_t stAB, size_t stS) {
  __shared__ __align__(16) unsigned short lds[32768];  // 64 KiB -> 2 blocks/CU
  char* ldsb = (char*)lds;
  const int t = threadIdx.x;
  const int lane = t & 63, w = t >> 6;
  const int l15 = lane & 15, lg = lane >> 4;
  const int wr = w >> 2, wc = w & 3;

  int m0, n0, qt = 0, kt = 0, z = 0;
  const unsigned short *A, *B;
  unsigned short* Co = nullptr;
  unsigned short* Sb = nullptr;
  if (MODE == 0) {
    const int o = blockIdx.x;
    const int oi = (o & 7) * 72 + (o >> 3);  // 576 = 8*72, bijective
    const int mt = oi / 9, sub = oi - mt * 9;
    const int ntile = sub / 3;
    z = sub - ntile * 3;
    if (z < 2) {
      m0 = mt * 256; n0 = ntile * 256;
      A = Ag; B = Bg + (size_t)z * DIM * DIM;
      Co = z == 0 ? o0 : o1;
    } else {
      m0 = ntile * 256; n0 = mt * 256;  // m: e-dim, n: s-dim
      A = Bg + (size_t)2 * DIM * DIM; B = Ag;
      Co = o2;
    }
  } else {
    const int i0 = blockIdx.x, b = blockIdx.y;
    const int i = (i0 & 7) * 17 + (i0 >> 3);  // 136 = 8*17, bijective
    qt = (int)((sqrtf(8.f * i + 1.f) - 1.f) * 0.5f);
    while ((qt + 1) * (qt + 2) / 2 <= i) ++qt;
    while (qt * (qt + 1) / 2 > i) --qt;
    kt = i - qt * (qt + 1) / 2;
    m0 = qt * 256; n0 = kt * 256;
    A = Ag + (size_t)b * stAB; B = Bg + (size_t)b * stAB;
    Sb = o0 + (size_t)b * stS;
  }

  const int cH = (((t & 3) ^ ((t >> 3) & 3)) << 3);         // stage src chunk (elems)
  const int sw = ((lg ^ ((l15 >> 1) & 3)) << 4);            // frag-read swizzle byte
  const int arb = (wr * 128 + l15) * 64 + sw;               // A frag base (f via +1024)
  const int brb = (wc * 64 + l15) * 64 + sw;                // B frag base (n via +1024)

  f32x4 acc[8][4];
#pragma unroll
  for (int f = 0; f < 8; ++f)
#pragma unroll
    for (int n = 0; n < 4; ++n) acc[f][n] = f32x4{0.f, 0.f, 0.f, 0.f};

  // prologue: tile0 -> buf0; drain; barrier
  STG_AB(A + (size_t)m0 * DIM + 0, B + (size_t)n0 * DIM + 0, DIM, 0);
  VMC0; SBAR;

  for (int tt = 0; tt < 23; ++tt) {
    const int bs = (tt & 1) * 32768;
    const int ts = ((tt + 1) & 1) * 32768;
    const int kb1 = (tt + 1) * 32;
    TILE32(bs,
           STG_AB(A + (size_t)m0 * DIM + kb1, B + (size_t)n0 * DIM + kb1, DIM, ts),
           VMC0, SBAR);
  }
  TILE32((23 & 1) * 32768, (void)0, (void)0, (void)0);

  if (MODE == 0) {
    if (z < 2) {
#pragma unroll
      for (int f = 0; f < 8; ++f) {
        const int row = m0 + wr * 128 + f * 16 + lg * 4;
#pragma unroll
        for (int n = 0; n < 4; ++n) {
          const int col = n0 + wc * 64 + n * 16 + l15;
#pragma unroll
          for (int ii = 0; ii < 4; ++ii)
            Co[(size_t)(row + ii) * DIM + col] = f2h(acc[f][n][ii]);
        }
      }
    } else {
      const int bb = n0 >> 12;
      unsigned short* O = Co + (size_t)bb * DIM * SLEN;
#pragma unroll
      for (int f = 0; f < 8; ++f) {
        const int row = m0 + wr * 128 + f * 16 + lg * 4;  // e
#pragma unroll
        for (int n = 0; n < 4; ++n) {
          const int sl = (n0 + wc * 64 + n * 16 + l15) & (SLEN - 1);
#pragma unroll
          for (int ii = 0; ii < 4; ++ii)
            O[(size_t)(row + ii) * SLEN + sl] = f2h(acc[f][n][ii]);
        }
      }
    }
  } else {
    const int Q128 = qt * 2 + wr;
    const int K128 = kt * 2 + (wc >> 1);
    if (K128 <= Q128) {
      const size_t tb = (size_t)(Q128 * (Q128 + 1) / 2 + K128) * 16384;
#pragma unroll
      for (int f = 0; f < 8; ++f) {
        const int rl = f * 16 + lg * 4;
#pragma unroll
        for (int n = 0; n < 4; ++n) {
          const int cl = ((wc & 1) * 64 + n * 16 + l15);
#pragma unroll
          for (int ii = 0; ii < 4; ++ii)
            Sb[tb + (size_t)(rl + ii) * 128 + cl] = f2h(acc[f][n][ii]);
        }
      }
    }
  }
}

// ---------------- row softmax (in-place, causal mask, normalize) ----------------
__global__ __launch_bounds__(256) void softmax_kernel(
    unsigned short* __restrict__ S, size_t s_bstride) {
  __shared__ float redm[4], reds[4];
  const int r = blockIdx.x, b = blockIdx.y;
  unsigned short* Sb = S + (size_t)b * s_bstride;
  const int qt = r >> 7, rl = r & 127;
  const int ncols = (qt + 1) * 128;
  const size_t rowbase = (size_t)(qt * (qt + 1) / 2) * 16384 + (size_t)rl * 128;
  const int t = threadIdx.x, lane = t & 63, w = t >> 6;
  const int c0 = t * 16;
  const bool act = c0 < ncols;
  const float NEG = -3.0e38f;
  float sv[16];
  unsigned short* p = nullptr;
  if (act) {
    int ktile = c0 >> 7, cl = c0 & 127;
    p = Sb + rowbase + (size_t)ktile * 16384 + cl;
    V8 v0, v1; v0.v = *(const short8*)p; v1.v = *(const short8*)(p + 8);
#pragma unroll
    for (int j = 0; j < 8; ++j) {
      sv[j] = (c0 + j > r) ? NEG : h2f(v0.u[j]);
      sv[8 + j] = (c0 + 8 + j > r) ? NEG : h2f(v1.u[j]);
    }
  } else {
#pragma unroll
    for (int j = 0; j < 16; ++j) sv[j] = NEG;
  }
  float mx = NEG;
#pragma unroll
  for (int j = 0; j < 16; ++j) mx = fmaxf(mx, sv[j]);
#pragma unroll
  for (int d = 1; d < 64; d <<= 1) mx = fmaxf(mx, __shfl_xor(mx, d));
  if (lane == 0) redm[w] = mx;
  __syncthreads();
  mx = fmaxf(fmaxf(redm[0], redm[1]), fmaxf(redm[2], redm[3]));
  const float scl = 1.4426950408889634f / 27.712812921102035f;  // log2(e)/sqrt(768)
  float e[16], sm = 0.f;
#pragma unroll
  for (int j = 0; j < 16; ++j) { e[j] = exp2f((sv[j] - mx) * scl); sm += e[j]; }
#pragma unroll
  for (int d = 1; d < 64; d <<= 1) sm += __shfl_xor(sm, d);
  if (lane == 0) reds[w] = sm;
  __syncthreads();
  float inv = 1.0f / (reds[0] + reds[1] + reds[2] + reds[3]);
  if (act) {
    V8 o0, o1;
#pragma unroll
    for (int j = 0; j < 8; ++j) { o0.u[j] = f2h(e[j] * inv); o1.u[j] = f2h(e[8 + j] * inv); }
    *(short8*)p = o0.v;
    *(short8*)(p + 8) = o1.v;
  }
}

// ---------------- zero the 128x128 f16 scratch tile ----------------
__global__ __launch_bounds__(256) void zero_tile_kernel(unsigned short* __restrict__ z) {
  ((short8*)z)[blockIdx.x * 256 + threadIdx.x] = short8{0, 0, 0, 0, 0, 0, 0, 0};
}

// ---------------- PV: 256x256 BK=32 double-buffer, balanced split-K ----------------
__device__ const int pv_mt[24]  = {15,15,7,14,14,13,13,6,12,12,11,11,5,10,10,9,9,4,8,8,3,2,1,0};
__device__ const int pv_ks0[24] = {0,64,0,0,60,0,56,0,0,52,0,48,0,0,44,0,40,0,0,36,0,0,0,0};
__device__ const int pv_kl[24]  = {64,64,64,60,60,56,56,56,52,52,48,48,48,44,44,40,40,40,36,36,32,24,16,8};
__device__ const int pv_sec[24] = {0,1,0,0,1,0,1,0,0,1,0,1,0,0,1,0,1,0,0,1,0,0,0,0};

__global__ __launch_bounds__(512, 4) void pv256_kernel(
    const unsigned short* __restrict__ S, const unsigned short* __restrict__ Vt,
    const unsigned short* __restrict__ Zt, float* __restrict__ Out,
    float* __restrict__ Part) {
  __shared__ __align__(16) unsigned short lds[32768];  // 64 KiB
  char* ldsb = (char*)lds;
  const int t = threadIdx.x, lane = t & 63, w = t >> 6;
  const int l15 = lane & 15, lg = lane >> 4;
  const int wr = w >> 2, wc = w & 3;
  const int rank = blockIdx.x / 12, sub = blockIdx.x % 12;
  const int b = sub / 3, nt = sub % 3;
  const int mt = pv_mt[rank], ks0 = pv_ks0[rank], kl = pv_kl[rank];
  const int sec = pv_sec[rank];
  const int q0 = 2 * mt, q1 = 2 * mt + 1;
  const unsigned short* Sbb = S + (size_t)b * SPB;
  const unsigned short* Vb = Vt + (size_t)b * DIM * SLEN + (size_t)(nt * 256) * SLEN;

  // A source for 32-wide k-step ks, 128-row half with Q128=qh; zero tile above diag.
  auto asrc = [&](int ks, int qh) -> const unsigned short* {
    const int K128 = ks >> 2;
    const unsigned short* base =
        (K128 <= qh) ? Sbb + (size_t)(qh * (qh + 1) / 2 + K128) * 16384 : Zt;
    return base + (ks & 3) * 32;
  };

  const int cH = (((t & 3) ^ ((t >> 3) & 3)) << 3);
  const int sw = ((lg ^ ((l15 >> 1) & 3)) << 4);
  const int arb = (wr * 128 + l15) * 64 + sw;
  const int brb = (wc * 64 + l15) * 64 + sw;

  f32x4 acc[8][4];
#pragma unroll
  for (int f = 0; f < 8; ++f)
#pragma unroll
    for (int n = 0; n < 4; ++n) acc[f][n] = f32x4{0.f, 0.f, 0.f, 0.f};

  // prologue: tile ks0 -> buf0; drain; barrier
  STG_PV(asrc(ks0, q0), asrc(ks0, q1), Vb + (size_t)ks0 * 32, 0);
  VMC0; SBAR;

  for (int it = 0; it < kl - 1; ++it) {
    const int bs = (it & 1) * 32768;
    const int ts = ((it + 1) & 1) * 32768;
    const int k1 = ks0 + it + 1;
    TILE32(bs,
           STG_PV(asrc(k1, q0), asrc(k1, q1), Vb + (size_t)k1 * 32, ts),
           VMC0, SBAR);
  }
  TILE32(((kl - 1) & 1) * 32768, (void)0, (void)0, (void)0);

  if (!sec) {
    float* Ob = Out + (size_t)b * SLEN * DIM + (size_t)(mt * 256) * DIM + nt * 256;
#pragma unroll
    for (int f = 0; f < 8; ++f) {
      const int rl = wr * 128 + f * 16 + lg * 4;
#pragma unroll
      for (int n = 0; n < 4; ++n) {
        const int cl = wc * 64 + n * 16 + l15;
#pragma unroll
        for (int ii = 0; ii < 4; ++ii)
          Ob[(size_t)(rl + ii) * DIM + cl] = acc[f][n][ii];
      }
    }
  } else {
    float* Pb = Part + (size_t)((b * 3 + nt) * 8 + (mt - 8)) * 65536;
#pragma unroll
    for (int f = 0; f < 8; ++f) {
      const int rl = wr * 128 + f * 16 + lg * 4;
#pragma unroll
      for (int n = 0; n < 4; ++n) {
        const int cl = wc * 64 + n * 16 + l15;
#pragma unroll
        for (int ii = 0; ii < 4; ++ii)
          Pb[(size_t)(rl + ii) * 256 + cl] = acc[f][n][ii];
      }
    }
  }
}

// ---------------- add secondary-segment partials into out ----------------
__global__ __launch_bounds__(256) void pv_reduce_kernel(
    const float* __restrict__ Part, float* __restrict__ Out) {
  const int bx = blockIdx.x;            // 0..6143
  const int p = bx >> 6;                // partial slot 0..95
  const int within = ((bx & 63) * 256 + threadIdx.x) * 4;
  const int mt = 8 + (p & 7);
  const int bnt = p >> 3, b = bnt / 3, nt = bnt % 3;
  const int r = within >> 8, c = within & 255;
  float* o = Out + (size_t)b * SLEN * DIM + (size_t)(mt * 256 + r) * DIM + nt * 256 + c;
  const f32x4 pv = *(const f32x4*)(Part + (size_t)p * 65536 + within);
  const f32x4 ov = *(const f32x4*)o;
  *(f32x4*)o = ov + pv;
}

// ---------------- fallback PV GEMM (packed P x Vt^T -> out fp32) ----------------
__global__ __launch_bounds__(256) void gemm_pv_kernel(
    const unsigned short* __restrict__ S, const unsigned short* __restrict__ Vt,
    float* __restrict__ Out, size_t s_bstride, int nb) {
  __shared__ __align__(16) unsigned short As[4096], Bs[4096];
  const int idx = blockIdx.x;
  const int qtr = idx / (6 * nb);
  const int rem = idx - qtr * 6 * nb;
  const int b = rem / 6, nt = rem % 6;
  const int qt = 31 - qtr;
  const unsigned short* Sb = S + (size_t)b * s_bstride + (size_t)(qt * (qt + 1) / 2) * 16384;
  const unsigned short* Vb = Vt + (size_t)b * DIM * SLEN + (size_t)(nt * 128) * SLEN;
  float* Ob = Out + (size_t)b * SLEN * DIM + (size_t)(qt * 128) * DIM + nt * 128;
  const int t = threadIdx.x, lane = t & 63, w = t >> 6;
  const int l15 = lane & 15, lg = lane >> 4;
  const int wm = w >> 1, wn = w & 1;
  f32x4 acc[4][4];
#pragma unroll
  for (int a = 0; a < 4; ++a)
#pragma unroll
    for (int b2 = 0; b2 < 4; ++b2) acc[a][b2] = f32x4{0.f, 0.f, 0.f, 0.f};
  const int c0 = t, c1 = t + 256;
  const int r0 = c0 >> 2, k80 = (c0 & 3) * 8;
  const int r1 = c1 >> 2, k81 = (c1 & 3) * 8;
  const int ksteps = (qt + 1) * 4;
  for (int ks = 0; ks < ksteps; ++ks) {
    const int kb = ks * 32;
    const size_t atile = (size_t)(kb >> 7) * 16384 + (size_t)(kb & 127);
    __syncthreads();
    gl_lds16(Sb + atile + (size_t)r0 * 128 + k80, As + (size_t)c0 * 8);
    gl_lds16(Sb + atile + (size_t)r1 * 128 + k81, As + (size_t)c1 * 8);
    gl_lds16(Vb + (size_t)r0 * SLEN + kb + k80, Bs + (size_t)c0 * 8);
    gl_lds16(Vb + (size_t)r1 * SLEN + kb + k81, Bs + (size_t)c1 * 8);
    __syncthreads();
    f16x8 a[4], bf[4];
#pragma unroll
    for (int mi = 0; mi < 4; ++mi)
      a[mi] = __builtin_bit_cast(f16x8, *(const short8*)(As + (wm * 64 + mi * 16 + l15) * 32 + lg * 8));
#pragma unroll
    for (int ni = 0; ni < 4; ++ni)
      bf[ni] = __builtin_bit_cast(f16x8, *(const short8*)(Bs + (wn * 64 + ni * 16 + l15) * 32 + lg * 8));
#pragma unroll
    for (int mi = 0; mi < 4; ++mi)
#pragma unroll
      for (int ni = 0; ni < 4; ++ni)
        acc[mi][ni] = __builtin_amdgcn_mfma_f32_16x16x32_f16(a[mi], bf[ni], acc[mi][ni], 0, 0, 0);
  }
#pragma unroll
  for (int mi = 0; mi < 4; ++mi)
#pragma unroll
    for (int ni = 0; ni < 4; ++ni)
#pragma unroll
      for (int ii = 0; ii < 4; ++ii) {
        int rl = wm * 64 + mi * 16 + lg * 4 + ii;
        int cl = wn * 64 + ni * 16 + l15;
        Ob[(size_t)rl * DIM + cl] = acc[mi][ni][ii];
      }
}

// ---------------- host launcher ----------------
extern "C" void kernel_launch(void* const* d_in, const int* in_sizes, int n_in,
                              void* d_out, int out_size, void* d_ws, size_t ws_size,
                              hipStream_t stream) {
  const float* x  = (const float*)d_in[0];
  const float* Wq = (const float*)d_in[1];
  const float* Wk = (const float*)d_in[2];
  const float* Wv = (const float*)d_in[3];
  float* out = (float*)d_out;

  const size_t n_x = (size_t)BATCH * SLEN * DIM;  // 12,582,912
  unsigned short* Q  = (unsigned short*)d_ws;
  unsigned short* K  = Q + n_x;
  unsigned short* Vt = K + n_x;
  unsigned short* xb = Vt + n_x;
  unsigned short* wt = xb + n_x;
  const size_t base_elems = 4 * n_x + (size_t)3 * DIM * DIM;  // 52,101,120
  const bool full = ws_size >= (base_elems + 4 * SPB) * 2;    // 173,408,256 B

  convert_x_kernel<<<dim3((unsigned)(n_x / 8 / 256)), 256, 0, stream>>>(x, xb);
  transpose_w_kernel<<<dim3(DIM / 32, DIM / 32, 3), 256, 0, stream>>>(Wq, Wk, Wv, wt);

  // merged QKV: Q,K row-major + V transposed, one 576-block dispatch
  gemm8_kernel<0><<<dim3(576), 512, 0, stream>>>(xb, wt, Q, K, Vt, 0, 0);

  if (full) {
    unsigned short* S = (unsigned short*)d_ws + base_elems;
    zero_tile_kernel<<<8, 256, 0, stream>>>(wt);  // wt dead; first 16384 -> zero tile
    gemm8_kernel<1><<<dim3(NT256, BATCH), 512, 0, stream>>>(
        Q, K, S, nullptr, nullptr, (size_t)SLEN * DIM, SPB);
    softmax_kernel<<<dim3(SLEN, BATCH), 256, 0, stream>>>(S, SPB);
    pv256_kernel<<<dim3(288), 512, 0, stream>>>(S, Vt, wt, out, (float*)xb);
    pv_reduce_kernel<<<dim3(6144), 256, 0, stream>>>((const float*)xb, out);
  } else {
    unsigned short* S = xb;  // overlay dead xb region (25.2 MB >= 17.3 MB)
    for (int b = 0; b < BATCH; ++b) {
      const size_t qo = (size_t)b * SLEN * DIM;
      gemm8_kernel<1><<<dim3(NT256, 1), 512, 0, stream>>>(
          Q + qo, K + qo, S, nullptr, nullptr, 0, 0);
      softmax_kernel<<<dim3(SLEN, 1), 256, 0, stream>>>(S, 0);
      gemm_pv_kernel<<<dim3(32 * 6), 256, 0, stream>>>(
          S, Vt + (size_t)b * DIM * SLEN, out + qo, 0, 1);
    }
  }
}

// Round 12
// 278.344 us; speedup vs baseline: 7.3864x; 7.3864x over previous
//
#include <hip/hip_runtime.h>
#include <hip/hip_bf16.h>
#include <hip/hip_fp16.h>

#define DIM 768
#define SLEN 4096
#define BATCH 4
#define NTILES 528   // 128-granular causal tiles per batch (S layout)
#define NT256 136    // 256-granular causal tiles per batch (qk grid)
#define SPB ((size_t)NTILES * 16384)

typedef __attribute__((ext_vector_type(8))) short short8;
typedef __attribute__((ext_vector_type(4))) short short4v;
typedef __attribute__((ext_vector_type(4))) float f32x4;
typedef __attribute__((ext_vector_type(8))) _Float16 f16x8;

typedef __attribute__((address_space(1))) void gvoid;
typedef __attribute__((address_space(3))) void lvoid;

__device__ __forceinline__ void gl_lds16(const void* g, void* l) {
  __builtin_amdgcn_global_load_lds((gvoid*)g, (lvoid*)l, 16, 0, 0);
}

__device__ __forceinline__ unsigned short f2h(float x) {
  union { _Float16 h; unsigned short u; } c; c.h = (_Float16)x; return c.u;
}
__device__ __forceinline__ float h2f(unsigned short u) {
  union { _Float16 h; unsigned short u; } c; c.u = u; return (float)c.h;
}

union V8 { short8 v; unsigned short u[8]; };

// ---------------- kernel 1: x fp32 -> fp16 ----------------
__global__ __launch_bounds__(256) void convert_x_kernel(
    const float* __restrict__ x, unsigned short* __restrict__ xb) {
  size_t i = ((size_t)blockIdx.x * 256 + threadIdx.x) * 8;
  f32x4 a = *(const f32x4*)(x + i);
  f32x4 b = *(const f32x4*)(x + i + 4);
  V8 o;
#pragma unroll
  for (int j = 0; j < 4; ++j) { o.u[j] = f2h(a[j]); o.u[4 + j] = f2h(b[j]); }
  *(short8*)(xb + i) = o.v;
}

// ---------------- kernel 2: W [k][n] fp32 -> Wt [n][k] fp16 ----------------
__global__ __launch_bounds__(256) void transpose_w_kernel(
    const float* __restrict__ Wq, const float* __restrict__ Wk,
    const float* __restrict__ Wv, unsigned short* __restrict__ Wt) {
  __shared__ float Tl[32][33];
  const float* Wi = blockIdx.z == 0 ? Wq : (blockIdx.z == 1 ? Wk : Wv);
  unsigned short* Wo = Wt + (size_t)blockIdx.z * DIM * DIM;
  int k0 = blockIdx.x * 32, n0 = blockIdx.y * 32;
  int t = threadIdx.x;
  int r = t >> 3, c4 = (t & 7) * 4;
  f32x4 v = *(const f32x4*)(Wi + (size_t)(k0 + r) * DIM + n0 + c4);
#pragma unroll
  for (int j = 0; j < 4; ++j) Tl[r][c4 + j] = v[j];
  __syncthreads();
  short4v ov;
#pragma unroll
  for (int j = 0; j < 4; ++j) ov[j] = (short)f2h(Tl[c4 + j][r]);
  *(short4v*)(Wo + (size_t)(n0 + r) * DIM + k0 + c4) = ov;
}

// ============ 256x256 GEMM core, group-pipelined, 1 barrier per K-tile ============
// (round-8 verified configuration: BK=64, 2 LDS buffers, drain-0 per tile.
// r10 ring-3 counted-vmcnt and r11 64KB/occupancy-4 both regressed — r11 spilled
// the 128-reg accumulator at the 128-VGPR clamp. This structure is register-capped
// at 2 waves/SIMD; barrier variants all land at MfmaUtil ~30%.)
// LDS: A buf p @ p*32768 (A0 +0, A1 +16384); B buf p @ 65536+p*32768.
// Fragment reads in 4 groups (8/4/8/4 ds_read_b128); each 16-MFMA cluster gated
// by counted lgkmcnt + sched_barrier(0). Tile boundary: vmcnt(0) then s_barrier.

#define STAGE(src, row0, kb, ldsoff)                                              \
  {                                                                               \
    gl_lds16((src) + (size_t)((row0) + rA) * DIM + (kb) + cA,                     \
             ldsb + (ldsoff) + t * 16);                                           \
    gl_lds16((src) + (size_t)((row0) + 64 + rA) * DIM + (kb) + cA,                \
             ldsb + (ldsoff) + 8192 + t * 16);                                    \
  }

#define STAGEP(srcp, stride, ldsoff)                                              \
  {                                                                               \
    gl_lds16((srcp) + (size_t)rA * (stride) + cA, ldsb + (ldsoff) + t * 16);      \
    gl_lds16((srcp) + (size_t)(64 + rA) * (stride) + cA,                          \
             ldsb + (ldsoff) + 8192 + t * 16);                                    \
  }

#define RDA(dst, base, chb)                                                       \
  _Pragma("unroll") for (int j = 0; j < 4; ++j)                                   \
      dst[j] = __builtin_bit_cast(f16x8, *(const short8*)(ldsb + (base) +         \
               (j * 32 + arow) * 128 + (chb)));

#define RDB(dst, base, chb)                                                       \
  _Pragma("unroll") for (int n = 0; n < 4; ++n)                                   \
      dst[n] = __builtin_bit_cast(f16x8, *(const short8*)(ldsb + (base) +         \
               bh * 16384 + (brow + n * 16) * 128 + (chb)));

#define MFMA16(af, bf, FO)                                                        \
  __builtin_amdgcn_s_setprio(1);                                                  \
  _Pragma("unroll") for (int j = 0; j < 4; ++j)                                   \
    _Pragma("unroll") for (int n = 0; n < 4; ++n)                                 \
      acc[(FO) + j][n] = __builtin_amdgcn_mfma_f32_16x16x32_f16(                  \
          af[j], bf[n], acc[(FO) + j][n], 0, 0, 0);                               \
  __builtin_amdgcn_s_setprio(0);

#define LGKM(N)                                                                   \
  asm volatile("s_waitcnt lgkmcnt(" #N ")" ::: "memory");                         \
  __builtin_amdgcn_sched_barrier(0);

#define TILE_BODY(aBx, bBx, STGB, STGA)                                           \
  {                                                                               \
    f16x8 a0_[4], a1_[4], a2_[4], a3_[4], b0_[4], b2_[4];                         \
    RDA(a0_, (aBx), ch0);                                                         \
    RDB(b0_, (bBx), ch0);                                                         \
    RDA(a1_, (aBx) + 16384, ch0);                                                 \
    STGB;                                                                         \
    LGKM(4); MFMA16(a0_, b0_, 0);                                                 \
    RDA(a2_, (aBx), ch0 ^ 64);                                                    \
    RDB(b2_, (bBx), ch0 ^ 64);                                                    \
    STGA;                                                                         \
    LGKM(8); MFMA16(a1_, b0_, 4);                                                 \
    RDA(a3_, (aBx) + 16384, ch0 ^ 64);                                            \
    LGKM(4); MFMA16(a2_, b2_, 0);                                                 \
    LGKM(0); MFMA16(a3_, b2_, 4);                                                 \
    asm volatile("s_waitcnt vmcnt(0)" ::: "memory");                              \
    asm volatile("s_barrier" ::: "memory");                                       \
  }

// MODE 0: merged qkv. 1-D grid 576, XCD-swizzled. z<2: C=A(xb)xB(wt_z)^T -> Q/K.
//         z==2: Vt[e][s] = A(wt_v) x B(xb)^T (swapped roles, out ld=SLEN).
// MODE 1: causal qk 256-tiles (x XCD-swizzled per batch) -> packed-128 S scatter.
template <int MODE>
__global__ __launch_bounds__(512, 2) void gemm8_kernel(
    const unsigned short* __restrict__ Ag, const unsigned short* __restrict__ Bg,
    unsigned short* __restrict__ o0, unsigned short* __restrict__ o1,
    unsigned short* __restrict__ o2, size_t stAB, size_t stS) {
  __shared__ __align__(16) unsigned short lds[65536];  // 128 KiB
  char* ldsb = (char*)lds;
  const int t = threadIdx.x;
  const int lane = t & 63, w = t >> 6;
  const int l15 = lane & 15, lg = lane >> 4;
  const int wr = w >> 2, wc = w & 3;

  int m0, n0, qt = 0, kt = 0, z = 0;
  const unsigned short *A, *B;
  unsigned short* Co = nullptr;
  unsigned short* Sb = nullptr;
  if (MODE == 0) {
    const int o = blockIdx.x;
    const int oi = (o & 7) * 72 + (o >> 3);  // 576 = 8*72, bijective
    const int mt = oi / 9, sub = oi - mt * 9;
    const int ntile = sub / 3;
    z = sub - ntile * 3;
    if (z < 2) {
      m0 = mt * 256; n0 = ntile * 256;
      A = Ag; B = Bg + (size_t)z * DIM * DIM;
      Co = z == 0 ? o0 : o1;
    } else {
      m0 = ntile * 256; n0 = mt * 256;  // m: e-dim, n: s-dim
      A = Bg + (size_t)2 * DIM * DIM; B = Ag;
      Co = o2;
    }
  } else {
    const int i0 = blockIdx.x, b = blockIdx.y;
    const int i = (i0 & 7) * 17 + (i0 >> 3);  // 136 = 8*17, bijective
    qt = (int)((sqrtf(8.f * i + 1.f) - 1.f) * 0.5f);
    while ((qt + 1) * (qt + 2) / 2 <= i) ++qt;
    while (qt * (qt + 1) / 2 > i) --qt;
    kt = i - qt * (qt + 1) / 2;
    m0 = qt * 256; n0 = kt * 256;
    A = Ag + (size_t)b * stAB; B = Bg + (size_t)b * stAB;
    Sb = o0 + (size_t)b * stS;
  }

  const int rA = t >> 3;
  const int cA = (((t & 7) ^ ((t >> 3) & 7)) << 3);  // inverse-swizzled src chunk
  const int ch0 = ((lg ^ (l15 & 7)) << 4);           // swizzled ds_read chunk byte
  const int arow = wr * 16 + l15;
  const int bh = wc >> 1;
  const int brow = (wc & 1) * 64 + l15;

  f32x4 acc[8][4];
#pragma unroll
  for (int f = 0; f < 8; ++f)
#pragma unroll
    for (int n = 0; n < 4; ++n) acc[f][n] = f32x4{0.f, 0.f, 0.f, 0.f};

  // prologue: full tile 0 into buf0
  STAGE(A, m0, 0, 0);
  STAGE(A, m0 + 128, 0, 16384);
  STAGE(B, n0, 0, 65536);
  STAGE(B, n0 + 128, 0, 65536 + 16384);
  asm volatile("s_waitcnt vmcnt(0)" ::: "memory");
  asm volatile("s_barrier" ::: "memory");

  for (int tt = 0; tt < 12; ++tt) {
    const int bt = tt & 1;
    const int aB = bt * 32768;
    const int bB = 65536 + bt * 32768;
    const int aN = (1 - bt) * 32768;
    const int bN = 65536 + (1 - bt) * 32768;
    const int kb1 = (tt + 1 < 12 ? tt + 1 : 11) * 64;
    TILE_BODY(aB, bB,
              STAGE(B, n0, kb1, bN); STAGE(B, n0 + 128, kb1, bN + 16384),
              STAGE(A, m0, kb1, aN); STAGE(A, m0 + 128, kb1, aN + 16384));
  }

  if (MODE == 0) {
    if (z < 2) {
#pragma unroll
      for (int f = 0; f < 8; ++f) {
        const int row = m0 + f * 32 + wr * 16 + lg * 4;
#pragma unroll
        for (int n = 0; n < 4; ++n) {
          const int col = n0 + wc * 64 + n * 16 + l15;
#pragma unroll
          for (int ii = 0; ii < 4; ++ii)
            Co[(size_t)(row + ii) * DIM + col] = f2h(acc[f][n][ii]);
        }
      }
    } else {
      const int bb = n0 >> 12;
      unsigned short* O = Co + (size_t)bb * DIM * SLEN;
#pragma unroll
      for (int f = 0; f < 8; ++f) {
        const int row = m0 + f * 32 + wr * 16 + lg * 4;  // e
#pragma unroll
        for (int n = 0; n < 4; ++n) {
          const int sl = (n0 + wc * 64 + n * 16 + l15) & (SLEN - 1);
#pragma unroll
          for (int ii = 0; ii < 4; ++ii)
            O[(size_t)(row + ii) * SLEN + sl] = f2h(acc[f][n][ii]);
        }
      }
    }
  } else {
#pragma unroll
    for (int f = 0; f < 8; ++f) {
      const int rl = (f * 32 + wr * 16 + lg * 4) & 127;
      const int Q128 = qt * 2 + (f >= 4 ? 1 : 0);
      const int K128 = kt * 2 + (wc >> 1);
      if (K128 > Q128) continue;
      const size_t tb = (size_t)(Q128 * (Q128 + 1) / 2 + K128) * 16384;
#pragma unroll
      for (int n = 0; n < 4; ++n) {
        const int cl = ((wc & 1) * 64 + n * 16 + l15);
#pragma unroll
        for (int ii = 0; ii < 4; ++ii)
          Sb[tb + (size_t)(rl + ii) * 128 + cl] = f2h(acc[f][n][ii]);
      }
    }
  }
}

// ---------------- row softmax (in-place, causal mask, normalize) ----------------
__global__ __launch_bounds__(256) void softmax_kernel(
    unsigned short* __restrict__ S, size_t s_bstride) {
  __shared__ float redm[4], reds[4];
  const int r = blockIdx.x, b = blockIdx.y;
  unsigned short* Sb = S + (size_t)b * s_bstride;
  const int qt = r >> 7, rl = r & 127;
  const int ncols = (qt + 1) * 128;
  const size_t rowbase = (size_t)(qt * (qt + 1) / 2) * 16384 + (size_t)rl * 128;
  const int t = threadIdx.x, lane = t & 63, w = t >> 6;
  const int c0 = t * 16;
  const bool act = c0 < ncols;
  const float NEG = -3.0e38f;
  float sv[16];
  unsigned short* p = nullptr;
  if (act) {
    int ktile = c0 >> 7, cl = c0 & 127;
    p = Sb + rowbase + (size_t)ktile * 16384 + cl;
    V8 v0, v1; v0.v = *(const short8*)p; v1.v = *(const short8*)(p + 8);
#pragma unroll
    for (int j = 0; j < 8; ++j) {
      sv[j] = (c0 + j > r) ? NEG : h2f(v0.u[j]);
      sv[8 + j] = (c0 + 8 + j > r) ? NEG : h2f(v1.u[j]);
    }
  } else {
#pragma unroll
    for (int j = 0; j < 16; ++j) sv[j] = NEG;
  }
  float mx = NEG;
#pragma unroll
  for (int j = 0; j < 16; ++j) mx = fmaxf(mx, sv[j]);
#pragma unroll
  for (int d = 1; d < 64; d <<= 1) mx = fmaxf(mx, __shfl_xor(mx, d));
  if (lane == 0) redm[w] = mx;
  __syncthreads();
  mx = fmaxf(fmaxf(redm[0], redm[1]), fmaxf(redm[2], redm[3]));
  const float scl = 1.4426950408889634f / 27.712812921102035f;  // log2(e)/sqrt(768)
  float e[16], sm = 0.f;
#pragma unroll
  for (int j = 0; j < 16; ++j) { e[j] = exp2f((sv[j] - mx) * scl); sm += e[j]; }
#pragma unroll
  for (int d = 1; d < 64; d <<= 1) sm += __shfl_xor(sm, d);
  if (lane == 0) reds[w] = sm;
  __syncthreads();
  float inv = 1.0f / (reds[0] + reds[1] + reds[2] + reds[3]);
  if (act) {
    V8 o0, o1;
#pragma unroll
    for (int j = 0; j < 8; ++j) { o0.u[j] = f2h(e[j] * inv); o1.u[j] = f2h(e[8 + j] * inv); }
    *(short8*)p = o0.v;
    *(short8*)(p + 8) = o1.v;
  }
}

// ---------------- zero the 128x128 f16 scratch tile ----------------
__global__ __launch_bounds__(256) void zero_tile_kernel(unsigned short* __restrict__ z) {
  ((short8*)z)[blockIdx.x * 256 + threadIdx.x] = short8{0, 0, 0, 0, 0, 0, 0, 0};
}

// ---------------- PV: 256x256 group-pipelined, balanced split-K ----------------
__device__ const int pv_mt[24]  = {15,15,7,14,14,13,13,6,12,12,11,11,5,10,10,9,9,4,8,8,3,2,1,0};
__device__ const int pv_ks0[24] = {0,32,0,0,30,0,28,0,0,26,0,24,0,0,22,0,20,0,0,18,0,0,0,0};
__device__ const int pv_kl[24]  = {32,32,32,30,30,28,28,28,26,26,24,24,24,22,22,20,20,20,18,18,16,12,8,4};
__device__ const int pv_sec[24] = {0,1,0,0,1,0,1,0,0,1,0,1,0,0,1,0,1,0,0,1,0,0,0,0};

__global__ __launch_bounds__(512, 2) void pv256_kernel(
    const unsigned short* __restrict__ S, const unsigned short* __restrict__ Vt,
    const unsigned short* __restrict__ Zt, float* __restrict__ Out,
    float* __restrict__ Part) {
  __shared__ __align__(16) unsigned short lds[65536];
  char* ldsb = (char*)lds;
  const int t = threadIdx.x, lane = t & 63, w = t >> 6;
  const int l15 = lane & 15, lg = lane >> 4;
  const int wr = w >> 2, wc = w & 3;
  const int rank = blockIdx.x / 12, sub = blockIdx.x % 12;
  const int b = sub / 3, nt = sub % 3;
  const int mt = pv_mt[rank], ks0 = pv_ks0[rank], kl = pv_kl[rank];
  const int sec = pv_sec[rank];
  const int q0 = 2 * mt, q1 = 2 * mt + 1;
  const int kend = ks0 + kl;
  const unsigned short* Sbb = S + (size_t)b * SPB;
  const unsigned short* Vb = Vt + (size_t)b * DIM * SLEN + (size_t)(nt * 256) * SLEN;

  auto asrc = [&](int ks, int qh) -> const unsigned short* {
    const int K128 = ks >> 1;
    const unsigned short* base =
        (K128 <= qh) ? Sbb + (size_t)(qh * (qh + 1) / 2 + K128) * 16384 : Zt;
    return base + (ks & 1) * 64;
  };

  const int rA = t >> 3;
  const int cA = (((t & 7) ^ ((t >> 3) & 7)) << 3);
  const int ch0 = ((lg ^ (l15 & 7)) << 4);
  const int arow = wr * 16 + l15;
  const int bh = wc >> 1;
  const int brow = (wc & 1) * 64 + l15;

  f32x4 acc[8][4];
#pragma unroll
  for (int f = 0; f < 8; ++f)
#pragma unroll
    for (int n = 0; n < 4; ++n) acc[f][n] = f32x4{0.f, 0.f, 0.f, 0.f};

  // prologue: full tile ks0 into buf0
  STAGEP(asrc(ks0, q0), 128, 0);
  STAGEP(asrc(ks0, q1), 128, 16384);
  STAGEP(Vb + (size_t)ks0 * 64, SLEN, 65536);
  STAGEP(Vb + (size_t)128 * SLEN + (size_t)ks0 * 64, SLEN, 65536 + 16384);
  asm volatile("s_waitcnt vmcnt(0)" ::: "memory");
  asm volatile("s_barrier" ::: "memory");

  for (int it = 0; it < kl; ++it) {
    const int ts = ks0 + it;
    const int bt = it & 1;
    const int aB = bt * 32768;
    const int bB = 65536 + bt * 32768;
    const int aN = (1 - bt) * 32768;
    const int bN = 65536 + (1 - bt) * 32768;
    const int t1 = (ts + 1 < kend) ? ts + 1 : kend - 1;
    TILE_BODY(aB, bB,
              STAGEP(Vb + (size_t)t1 * 64, SLEN, bN);
              STAGEP(Vb + (size_t)128 * SLEN + (size_t)t1 * 64, SLEN, bN + 16384),
              STAGEP(asrc(t1, q0), 128, aN);
              STAGEP(asrc(t1, q1), 128, aN + 16384));
  }

  if (!sec) {
    float* Ob = Out + (size_t)b * SLEN * DIM + (size_t)(mt * 256) * DIM + nt * 256;
#pragma unroll
    for (int f = 0; f < 8; ++f) {
      const int rl = f * 32 + wr * 16 + lg * 4;
#pragma unroll
      for (int n = 0; n < 4; ++n) {
        const int cl = wc * 64 + n * 16 + l15;
#pragma unroll
        for (int ii = 0; ii < 4; ++ii)
          Ob[(size_t)(rl + ii) * DIM + cl] = acc[f][n][ii];
      }
    }
  } else {
    float* Pb = Part + (size_t)((b * 3 + nt) * 8 + (mt - 8)) * 65536;
#pragma unroll
    for (int f = 0; f < 8; ++f) {
      const int rl = f * 32 + wr * 16 + lg * 4;
#pragma unroll
      for (int n = 0; n < 4; ++n) {
        const int cl = wc * 64 + n * 16 + l15;
#pragma unroll
        for (int ii = 0; ii < 4; ++ii)
          Pb[(size_t)(rl + ii) * 256 + cl] = acc[f][n][ii];
      }
    }
  }
}

// ---------------- add secondary-segment partials into out ----------------
__global__ __launch_bounds__(256) void pv_reduce_kernel(
    const float* __restrict__ Part, float* __restrict__ Out) {
  const int bx = blockIdx.x;            // 0..6143
  const int p = bx >> 6;                // partial slot 0..95
  const int within = ((bx & 63) * 256 + threadIdx.x) * 4;
  const int mt = 8 + (p & 7);
  const int bnt = p >> 3, b = bnt / 3, nt = bnt % 3;
  const int r = within >> 8, c = within & 255;
  float* o = Out + (size_t)b * SLEN * DIM + (size_t)(mt * 256 + r) * DIM + nt * 256 + c;
  const f32x4 pv = *(const f32x4*)(Part + (size_t)p * 65536 + within);
  const f32x4 ov = *(const f32x4*)o;
  *(f32x4*)o = ov + pv;
}

// ---------------- fallback PV GEMM (packed P x Vt^T -> out fp32) ----------------
__global__ __launch_bounds__(256) void gemm_pv_kernel(
    const unsigned short* __restrict__ S, const unsigned short* __restrict__ Vt,
    float* __restrict__ Out, size_t s_bstride, int nb) {
  __shared__ __align__(16) unsigned short As[4096], Bs[4096];
  const int idx = blockIdx.x;
  const int qtr = idx / (6 * nb);
  const int rem = idx - qtr * 6 * nb;
  const int b = rem / 6, nt = rem % 6;
  const int qt = 31 - qtr;
  const unsigned short* Sb = S + (size_t)b * s_bstride + (size_t)(qt * (qt + 1) / 2) * 16384;
  const unsigned short* Vb = Vt + (size_t)b * DIM * SLEN + (size_t)(nt * 128) * SLEN;
  float* Ob = Out + (size_t)b * SLEN * DIM + (size_t)(qt * 128) * DIM + nt * 128;
  const int t = threadIdx.x, lane = t & 63, w = t >> 6;
  const int l15 = lane & 15, lg = lane >> 4;
  const int wm = w >> 1, wn = w & 1;
  f32x4 acc[4][4];
#pragma unroll
  for (int a = 0; a < 4; ++a)
#pragma unroll
    for (int b2 = 0; b2 < 4; ++b2) acc[a][b2] = f32x4{0.f, 0.f, 0.f, 0.f};
  const int c0 = t, c1 = t + 256;
  const int r0 = c0 >> 2, k80 = (c0 & 3) * 8;
  const int r1 = c1 >> 2, k81 = (c1 & 3) * 8;
  const int ksteps = (qt + 1) * 4;
  for (int ks = 0; ks < ksteps; ++ks) {
    const int kb = ks * 32;
    const size_t atile = (size_t)(kb >> 7) * 16384 + (size_t)(kb & 127);
    __syncthreads();
    gl_lds16(Sb + atile + (size_t)r0 * 128 + k80, As + (size_t)c0 * 8);
    gl_lds16(Sb + atile + (size_t)r1 * 128 + k81, As + (size_t)c1 * 8);
    gl_lds16(Vb + (size_t)r0 * SLEN + kb + k80, Bs + (size_t)c0 * 8);
    gl_lds16(Vb + (size_t)r1 * SLEN + kb + k81, Bs + (size_t)c1 * 8);
    __syncthreads();
    f16x8 a[4], bf[4];
#pragma unroll
    for (int mi = 0; mi < 4; ++mi)
      a[mi] = __builtin_bit_cast(f16x8, *(const short8*)(As + (wm * 64 + mi * 16 + l15) * 32 + lg * 8));
#pragma unroll
    for (int ni = 0; ni < 4; ++ni)
      bf[ni] = __builtin_bit_cast(f16x8, *(const short8*)(Bs + (wn * 64 + ni * 16 + l15) * 32 + lg * 8));
#pragma unroll
    for (int mi = 0; mi < 4; ++mi)
#pragma unroll
      for (int ni = 0; ni < 4; ++ni)
        acc[mi][ni] = __builtin_amdgcn_mfma_f32_16x16x32_f16(a[mi], bf[ni], acc[mi][ni], 0, 0, 0);
  }
#pragma unroll
  for (int mi = 0; mi < 4; ++mi)
#pragma unroll
    for (int ni = 0; ni < 4; ++ni)
#pragma unroll
      for (int ii = 0; ii < 4; ++ii) {
        int rl = wm * 64 + mi * 16 + lg * 4 + ii;
        int cl = wn * 64 + ni * 16 + l15;
        Ob[(size_t)rl * DIM + cl] = acc[mi][ni][ii];
      }
}

// ---------------- host launcher ----------------
extern "C" void kernel_launch(void* const* d_in, const int* in_sizes, int n_in,
                              void* d_out, int out_size, void* d_ws, size_t ws_size,
                              hipStream_t stream) {
  const float* x  = (const float*)d_in[0];
  const float* Wq = (const float*)d_in[1];
  const float* Wk = (const float*)d_in[2];
  const float* Wv = (const float*)d_in[3];
  float* out = (float*)d_out;

  const size_t n_x = (size_t)BATCH * SLEN * DIM;  // 12,582,912
  unsigned short* Q  = (unsigned short*)d_ws;
  unsigned short* K  = Q + n_x;
  unsigned short* Vt = K + n_x;
  unsigned short* xb = Vt + n_x;
  unsigned short* wt = xb + n_x;
  const size_t base_elems = 4 * n_x + (size_t)3 * DIM * DIM;  // 52,101,120
  const bool full = ws_size >= (base_elems + 4 * SPB) * 2;    // 173,408,256 B

  convert_x_kernel<<<dim3((unsigned)(n_x / 8 / 256)), 256, 0, stream>>>(x, xb);
  transpose_w_kernel<<<dim3(DIM / 32, DIM / 32, 3), 256, 0, stream>>>(Wq, Wk, Wv, wt);

  // merged QKV: Q,K row-major + V transposed, one 576-block dispatch
  gemm8_kernel<0><<<dim3(576), 512, 0, stream>>>(xb, wt, Q, K, Vt, 0, 0);

  if (full) {
    unsigned short* S = (unsigned short*)d_ws + base_elems;
    zero_tile_kernel<<<8, 256, 0, stream>>>(wt);  // wt dead; first 16384 -> zero tile
    gemm8_kernel<1><<<dim3(NT256, BATCH), 512, 0, stream>>>(
        Q, K, S, nullptr, nullptr, (size_t)SLEN * DIM, SPB);
    softmax_kernel<<<dim3(SLEN, BATCH), 256, 0, stream>>>(S, SPB);
    pv256_kernel<<<dim3(288), 512, 0, stream>>>(S, Vt, wt, out, (float*)xb);
    pv_reduce_kernel<<<dim3(6144), 256, 0, stream>>>((const float*)xb, out);
  } else {
    unsigned short* S = xb;  // overlay dead xb region (25.2 MB >= 17.3 MB)
    for (int b = 0; b < BATCH; ++b) {
      const size_t qo = (size_t)b * SLEN * DIM;
      gemm8_kernel<1><<<dim3(NT256, 1), 512, 0, stream>>>(
          Q + qo, K + qo, S, nullptr, nullptr, 0, 0);
      softmax_kernel<<<dim3(SLEN, 1), 256, 0, stream>>>(S, 0);
      gemm_pv_kernel<<<dim3(32 * 6), 256, 0, stream>>>(
          S, Vt + (size_t)b * DIM * SLEN, out + qo, 0, 1);
    }
  }
}